// Round 18
// baseline (2015.146 us; speedup 1.0000x reference)
//
#include <hip/hip_runtime.h>
#include <math.h>

#define NROW  131072
#define DIMC  64
#define KCODE 512
#define BM    64              // rows per block (4 waves x 16)
#define RPW   16              // rows per wave
#define NBLK  (NROW / BM)     // 2048 blocks

typedef float f32x4 __attribute__((ext_vector_type(4)));

// ---- prep: e2[k] = sum_d e[d][k]^2 (sequential d), eT[k][d] = e[d][k], zero dacc
__global__ void prep_kernel(const float* __restrict__ e, float* __restrict__ e2,
                            float* __restrict__ eT, double* __restrict__ dacc) {
  int k = blockIdx.x * 256 + threadIdx.x;
  if (k == 0) *dacc = 0.0;
  if (k < KCODE) {
    float s = 0.f;
    for (int d = 0; d < DIMC; ++d) {
      float v = e[d * KCODE + k];           // coalesced across k
      s = __fadd_rn(s, __fmul_rn(v, v));    // same chain as reference (ef*ef).sum(0)
      eT[k * DIMC + d] = v;                 // transposed codebook for epilogue gather
    }
    e2[k] = s;
  }
}

// ---- ss[row] = sum_d x[row][d]^2, sequential d ascending
__global__ void ss_kernel(const float* __restrict__ x, float* __restrict__ ss) {
  int row = blockIdx.x * 256 + threadIdx.x;
  const float* xr = x + (long)row * DIMC;
  float s = 0.f;
#pragma unroll
  for (int d0 = 0; d0 < DIMC; d0 += 4) {
    f32x4 v = *(const f32x4*)(xr + d0);
    s = __fadd_rn(s, __fmul_rn(v[0], v[0]));
    s = __fadd_rn(s, __fmul_rn(v[1], v[1]));
    s = __fadd_rn(s, __fmul_rn(v[2], v[2]));
    s = __fadd_rn(s, __fmul_rn(v[3], v[3]));
  }
  ss[row] = s;
}

// ---- main: A from LDS via wave-uniform ds_read_b128 broadcasts (conflict-free),
// B per-lane coalesced in registers (L1/L2-resident e), lane = code column.
// R15 bug: staging wrote only 1024 of 4096 floats (missing 4x loop) -> idx garbage.
__global__ void __launch_bounds__(256)
quant_kernel(const float* __restrict__ x, const float* __restrict__ e,
             const float* __restrict__ e2, const float* __restrict__ eT,
             const float* __restrict__ ss, float* __restrict__ out,
             float* __restrict__ oidx, double* __restrict__ dacc) {
  __shared__ float xs[BM][DIMC];            // 16 KB, row-major
  const int t    = threadIdx.x;
  const int lane = t & 63;
  const int w    = t >> 6;                  // wave 0..3
  const long base = (long)blockIdx.x * BM * DIMC;

  // stage FULL x-tile: 4 float4 per thread, 1024 float4s = 64x64 floats, linear
#pragma unroll
  for (int i = 0; i < 4; ++i) {
    int f = t + i * 256;                    // float4 index 0..1023
    int row = f >> 4, c0 = (f & 15) * 4;
    *(f32x4*)&xs[row][c0] = *(const f32x4*)(x + base + (long)f * 4);
  }
  __syncthreads();

  const int rw = w * RPW;                   // wave's row offset in tile
  const long r0 = (long)blockIdx.x * BM + rw;

  float ssr[RPW];
#pragma unroll
  for (int r = 0; r < RPW; ++r) ssr[r] = ss[r0 + r];

  float minv[RPW];
  int   mini[RPW];
#pragma unroll
  for (int r = 0; r < RPW; ++r) { minv[r] = INFINITY; mini[r] = 0; }

  // 4 passes x 2 col-tiles: cols cA = T2*128+lane, cB = cA+64
  for (int T2 = 0; T2 < 4; ++T2) {
    const int cA = T2 * 128 + lane;
    const float* eA = e + cA;

    float accA[RPW], accB[RPW];
#pragma unroll
    for (int r = 0; r < RPW; ++r) { accA[r] = 0.f; accB[r] = 0.f; }

#pragma unroll
    for (int d0 = 0; d0 < DIMC; d0 += 4) {
      // B: 8 coalesced per-lane dword loads (2 cols x 4 d), L1/L2-resident
      float bA0 = eA[(d0 + 0) * KCODE],      bB0 = eA[(d0 + 0) * KCODE + 64];
      float bA1 = eA[(d0 + 1) * KCODE],      bB1 = eA[(d0 + 1) * KCODE + 64];
      float bA2 = eA[(d0 + 2) * KCODE],      bB2 = eA[(d0 + 2) * KCODE + 64];
      float bA3 = eA[(d0 + 3) * KCODE],      bB3 = eA[(d0 + 3) * KCODE + 64];
#pragma unroll
      for (int r = 0; r < RPW; ++r) {
        // A: 16B wave-uniform LDS broadcast -> 8 FMAs per ds_read_b128
        f32x4 av = *(const f32x4*)&xs[rw + r][d0];
        accA[r] = fmaf(av[0], bA0, accA[r]);   // d-ascending chain == ref numerics
        accA[r] = fmaf(av[1], bA1, accA[r]);
        accA[r] = fmaf(av[2], bA2, accA[r]);
        accA[r] = fmaf(av[3], bA3, accA[r]);
        accB[r] = fmaf(av[0], bB0, accB[r]);
        accB[r] = fmaf(av[1], bB1, accB[r]);
        accB[r] = fmaf(av[2], bB2, accB[r]);
        accB[r] = fmaf(av[3], bB3, accB[r]);
      }
    }

    const float e2A = e2[cA];
    const float e2B = e2[cA + 64];
#pragma unroll
    for (int r = 0; r < RPW; ++r) {
      // replicate reference rounding: fl(fl(ss - 2*dot) + e2); cA < cB checked first
      float dA = __fadd_rn(__fsub_rn(ssr[r], __fmul_rn(2.0f, accA[r])), e2A);
      if (dA < minv[r]) { minv[r] = dA; mini[r] = cA; }
      float dB = __fadd_rn(__fsub_rn(ssr[r], __fmul_rn(2.0f, accB[r])), e2B);
      if (dB < minv[r]) { minv[r] = dB; mini[r] = cA + 64; }
    }
  }

  // cross-lane argmin per row (tie -> lowest col == argmin-first semantics)
#pragma unroll
  for (int off = 1; off < 64; off <<= 1) {
#pragma unroll
    for (int r = 0; r < RPW; ++r) {
      float ov = __shfl_xor(minv[r], off, 64);
      int   oi = __shfl_xor(mini[r], off, 64);
      if (ov < minv[r] || (ov == minv[r] && oi < mini[r])) {
        minv[r] = ov; mini[r] = oi;
      }
    }
  }

  // epilogue: out = x + (q - x), idx, diff partial; xv comes from LDS
  double dsum = 0.0;
#pragma unroll
  for (int r = 0; r < RPW; ++r) {
    const long row = r0 + r;
    const int  idx = mini[r];
    float xv = xs[rw + r][lane];                // LDS, stride-1 across lanes
    float q  = eT[(long)idx * DIMC + lane];     // coalesced gather, L2-resident
    out[row * DIMC + lane] = __fadd_rn(xv, __fsub_rn(q, xv));
    float dq = __fsub_rn(q, xv);
    dsum += (double)__fmul_rn(dq, dq);
    if (lane == 0) oidx[row] = (float)idx;
  }
#pragma unroll
  for (int off = 32; off > 0; off >>= 1)
    dsum += __shfl_down(dsum, off, 64);
  if (lane == 0) atomicAdd(dacc, dsum);
}

// ---- finalize diff + (constant) perplexity
__global__ void fin_kernel(const double* __restrict__ dacc,
                           float* __restrict__ diff_out,
                           float* __restrict__ perp_out) {
  double s = *dacc;
  *diff_out = (float)(s / 8388608.0);
  float p = 1.0f / 512.0f;          // mean(one_hot) == 1/K exactly (reference quirk)
  float lp = logf(p + 1e-10f);
  *perp_out = expf(-(p * lp));
}

extern "C" void kernel_launch(void* const* d_in, const int* in_sizes, int n_in,
                              void* d_out, int out_size, void* d_ws, size_t ws_size,
                              hipStream_t stream) {
  const float* x = (const float*)d_in[0];   // [32,64,64,64]
  const float* e = (const float*)d_in[1];   // [1,1,64,512]
  float* out  = (float*)d_out;              // out | diff | idx | perp
  float* diff = out + 8388608;
  float* oidx = out + 8388609;
  float* perp = out + 8388609 + 131072;

  float*  e2   = (float*)d_ws;                          // 512 f   @ 0
  double* dacc = (double*)((char*)d_ws + 2048);         // 8 B     @ 2048
  float*  eT   = (float*)((char*)d_ws + 4096);          // 128 KiB @ 4096
  float*  ss   = (float*)((char*)d_ws + 4096 + 131072); // 512 KiB

  prep_kernel<<<2, 256, 0, stream>>>(e, e2, eT, dacc);
  ss_kernel<<<NROW / 256, 256, 0, stream>>>(x, ss);
  quant_kernel<<<NBLK, 256, 0, stream>>>(x, e, e2, eT, ss, out, oidx, dacc);
  fin_kernel<<<1, 1, 0, stream>>>(dacc, diff, perp);
}